// Round 8
// baseline (831.965 us; speedup 1.0000x reference)
//
#include <hip/hip_runtime.h>
#include <hip/hip_bf16.h>

// Problem: B=8192 rows, D=4096. 3 layers of relu(l2norm(h) @ W^T + b).
// ROUND 8 = ROUND 7 + prologue fix. B (weights) is pre-cast into MFMA-
// fragment-tiled bf16 (fragment (nb,kb) = 64 lanes x 16B contiguous) and
// loaded straight from global/L2 as coalesced dwordx4 -- B never touches
// LDS. LDS holds A only (64 KiB double-buffer). Rationale (R6 counters):
// LDS pipe (24 b128/wave + B staging writes -> ~2816 cyc/tile/CU) exceeded
// the MFMA pipe (2483 cyc) -- kernel was LDS-BW-bound. Now LDS ~1790 cyc.
// R7 FAILED (absmax 1.8e37): prologue used counted VMW(4) assuming
// stage_A issued before the b01 reg-loads; compiler may reorder the two
// (no alias, no fence) -> vmcnt(4) retired b01 instead of A(0) -> the aX
// pre-read consumed unlanded LDS. Fix: prologue drains vmcnt(0) (one-time
// cost). Steady state never relies on counted-wait issue order: all LDS
// reads of staged data sit behind mid VMW(0)+BARRIER; b01/b23 VGPR loads
// are compiler-protected.

#define NROWS 8192
#define DIM   4096

typedef __bf16 bf16x8 __attribute__((ext_vector_type(8)));
typedef float  f32x4  __attribute__((ext_vector_type(4)));
typedef short  short8 __attribute__((ext_vector_type(8)));

__device__ static inline short f2bf(float f) {
  __hip_bfloat16 h = __float2bfloat16(f);
  return __builtin_bit_cast(short, h);
}

#define BARRIER() do { asm volatile("" ::: "memory"); \
                       __builtin_amdgcn_s_barrier();  \
                       asm volatile("" ::: "memory"); } while (0)
#define GATE()   do { asm volatile("s_waitcnt lgkmcnt(0)" ::: "memory"); \
                      __builtin_amdgcn_sched_barrier(0); } while (0)
#define VMW(N)   do { asm volatile("s_waitcnt vmcnt(" #N ")" ::: "memory"); \
                      __builtin_amdgcn_sched_barrier(0); } while (0)

// ---------------------------------------------------------------------------
// C[M,N] = relu(A[M,K](bf16) . Wt(frag-tiled bf16) + bias[N]), fp32 out.
// 8 waves 2(M)x4(N); per-wave 128x64 out = acc[8][4].
// Wt layout: frag f = nb*(K/32)+kb; byte = f*1024 + lane*16; lane l holds
// rows nb*16+(l&15), k = kb*32+(l>>4)*8 .. +8 (matches MFMA B operand).
//
// Per tile t (A buf = t&1), 4 clusters c1..c4 of 16 MFMA:
//  top: issue b23(t) | stage A(t+1) | vmcnt(8|4) [perf gate] | lgkm0 [aX]
//  c1 : window aY(t) ds_read x8 | MFMA16(acc[0..3][0..1], aX, b01) | lgkm0
//  c2 : MFMA16(acc[4..7][0..1], aY, b01)                 [b01 dead]
//  mid: vmcnt(0) [b23(t)+A(t+1) land -- order-independent] | BAR [publish]
//  c3 : window issue b01(t+1) | MFMA16(acc[0..3][2..3], aX, b23) [aX dead]
//  c4 : window aX(t+1) ds_read x8 | MFMA16(acc[4..7][2..3], aY, b23)
// LDS-validity chain (the only waits that MUST be correct):
//   A(t+1) staged at top(t) -> mid(t) VMW(0) + BARRIER -> read c4(t) aX
//   and c1(t+1) aY. Prologue: stage A(0) -> VMW(0) + BARRIER -> aX read.
// WAR(A-stage top(t) into buf cur^1 holding A(t-1)): its readers' lgkm0
// gates all precede mid-BARRIER(t-1) < top(t).  Reg WAR: SSA/allocator.
// ---------------------------------------------------------------------------
__global__ __launch_bounds__(512, 2)
void gemm256_bias_relu(const short* __restrict__ A,
                       const short* __restrict__ Wt,
                       const float* __restrict__ bias,
                       float* __restrict__ C,
                       int M, int N, int K)
{
  __shared__ short lds[2][16384];   // A only: 2 bufs x 256 rows x 64 bf16 = 64 KiB

  // XCD-aware swizzle (bijective: grid % 8 == 0 here)
  int bid = blockIdx.x;
  const int nwg = gridDim.x;
  if ((nwg & 7) == 0) { const int cpx = nwg >> 3; bid = (bid & 7) * cpx + (bid >> 3); }
  const int nbn  = N >> 8;
  const int brow = (bid / nbn) << 8;
  const int bcol = (bid % nbn) << 8;

  const int lane = threadIdx.x & 63;
  const int wid  = threadIdx.x >> 6;   // 0..7
  const int wr   = wid >> 2;           // 0..1 : 128-row band
  const int wc   = wid & 3;            // 0..3 : 64-col band

  f32x4 acc[8][4] = {};

  const size_t rowK = (size_t)K * 2;   // bytes per A row
  char* const  ldsB = (char*)&lds[0][0];

  // ---- A staging (coalesced, source pre-swizzled) ----
  const int r8  = lane >> 3;
  const int kcs = (lane & 7) ^ r8;
  const char* AgL = (const char*)A + (size_t)(brow + r8) * rowK + (size_t)kcs * 16;
  int rbo[4], rbb[4];
#pragma unroll
  for (int i = 0; i < 4; ++i) {
    const int rb = wid * 8 + i * 64;
    rbo[i] = rb * (int)rowK;
    rbb[i] = rb * 128;
  }
  auto stage_A = [&](int parity, int tile) {
    const char* gp = AgL + ((size_t)tile << 7);
    char* lb = ldsB + parity * 32768;
#pragma unroll
    for (int s = 0; s < 4; ++s)
      __builtin_amdgcn_global_load_lds(
          (const __attribute__((address_space(1))) void*)(gp + rbo[s]),
          (__attribute__((address_space(3))) void*)(lb + rbb[s]), 16, 0, 0);
  };

  // ---- A fragment reads (XOR-swizzled LDS, as R6) ----
  const int l15  = lane & 15;
  const int xlo  = ((lane >> 4) ^ (lane & 3)) * 16;
  const int b2   = (lane >> 2) & 1;
  const int k64[2] = { b2 << 6, (1 - b2) << 6 };
  const int abase = (wr * 128 + l15) * 128 + xlo;

  // ---- B fragment pointers (frag-tiled global; coalesced) ----
  const int KB = K >> 5;               // frags per nb (kb count)
  const int nbase = (bcol >> 4) + wc * 4;
  const char* pB0 = (const char*)Wt + ((size_t)(nbase + 0) * KB * 64 + lane) * 16;
  const char* pB1 = (const char*)Wt + ((size_t)(nbase + 1) * KB * 64 + lane) * 16;
  const char* pB2 = (const char*)Wt + ((size_t)(nbase + 2) * KB * 64 + lane) * 16;
  const char* pB3 = (const char*)Wt + ((size_t)(nbase + 3) * KB * 64 + lane) * 16;

  const int NT = K >> 6;

  bf16x8 aX[4][2], aY[4][2], b01[2][2], b23[2][2];

#define LOAD_AF(DST, PTR, I0)                                                \
  _Pragma("unroll")                                                          \
  for (int ii = 0; ii < 4; ++ii)                                             \
    _Pragma("unroll")                                                        \
    for (int ks = 0; ks < 2; ++ks)                                           \
      DST[ii][ks] = *reinterpret_cast<const bf16x8*>(                        \
          (PTR) + abase + ((I0) + ii) * 2048 + k64[ks]);

#define LOAD_BP(DST, PJ0, PJ1, TOFF)                                         \
  DST[0][0] = *reinterpret_cast<const bf16x8*>((PJ0) + (TOFF));              \
  DST[0][1] = *reinterpret_cast<const bf16x8*>((PJ0) + (TOFF) + 1024);       \
  DST[1][0] = *reinterpret_cast<const bf16x8*>((PJ1) + (TOFF));              \
  DST[1][1] = *reinterpret_cast<const bf16x8*>((PJ1) + (TOFF) + 1024);

#define MFMA16(I0, AF, J0, BF)                                               \
  _Pragma("unroll")                                                          \
  for (int ks = 0; ks < 2; ++ks)                                             \
    _Pragma("unroll")                                                        \
    for (int ii = 0; ii < 4; ++ii)                                           \
      _Pragma("unroll")                                                      \
      for (int jj = 0; jj < 2; ++jj)                                         \
        acc[(I0) + ii][(J0) + jj] = __builtin_amdgcn_mfma_f32_16x16x32_bf16( \
            AF[ii][ks], BF[jj][ks], acc[(I0) + ii][(J0) + jj], 0, 0, 0);

  // ---- prologue: stage A(0); issue b01(0); DRAIN vmcnt(0) (R8 fix: a
  //      counted wait here would depend on compiler issue order of
  //      independent VMEM ops -- the R7 bug); publish; pre-read aX(0) ----
  stage_A(0, 0);
  LOAD_BP(b01, pB0, pB1, 0)
  VMW(0);
  BARRIER();
  LOAD_AF(aX, ldsB, 0)

  for (int t = 0; t < NT; ++t) {
    const int cur = t & 1;
    const char* At = ldsB + cur * 32768;
    const char* An = ldsB + (cur ^ 1) * 32768;
    const size_t toff = (size_t)t << 11;

    // ---- top ----
    LOAD_BP(b23, pB2, pB3, toff)
    if (t + 1 < NT) { stage_A(cur ^ 1, t + 1); VMW(8); }
    else            { VMW(4); }
    GATE();                              // aX(t) ready
    // ---- c1 ----
    LOAD_AF(aY, At, 4)
    __builtin_amdgcn_s_setprio(1);
    MFMA16(0, aX, 0, b01)
    __builtin_amdgcn_s_setprio(0);
    GATE();                              // aY ready
    // ---- c2 ----
    __builtin_amdgcn_s_setprio(1);
    MFMA16(4, aY, 0, b01)
    __builtin_amdgcn_s_setprio(0);
    // ---- mid: land b23(t) + A(t+1) (order-independent); publish ----
    VMW(0);
    BARRIER();
    // ---- c3 ----
    if (t + 1 < NT) { LOAD_BP(b01, pB0, pB1, toff + 2048) }
    __builtin_amdgcn_s_setprio(1);
    MFMA16(0, aX, 2, b23)
    __builtin_amdgcn_s_setprio(0);
    // ---- c4 ----
    if (t + 1 < NT) { LOAD_AF(aX, An, 0) }
    __builtin_amdgcn_s_setprio(1);
    MFMA16(4, aY, 2, b23)
    __builtin_amdgcn_s_setprio(0);
  }
#undef MFMA16
#undef LOAD_AF
#undef LOAD_BP

  // epilogue (bias loaded here to keep loop regs lean)
  float bv[4];
#pragma unroll
  for (int j = 0; j < 4; ++j)
    bv[j] = bias[bcol + wc * 64 + j * 16 + (lane & 15)];
#pragma unroll
  for (int i = 0; i < 8; ++i) {
    const int rbase = brow + wr * 128 + i * 16 + ((lane >> 4) << 2);
#pragma unroll
    for (int j = 0; j < 4; ++j) {
      const int col = bcol + wc * 64 + j * 16 + (lane & 15);
#pragma unroll
      for (int r = 0; r < 4; ++r) {
        const float v = acc[i][j][r] + bv[j];
        C[(size_t)(rbase + r) * N + col] = v > 0.f ? v : 0.f;
      }
    }
  }
}

// ---------------------------------------------------------------------------
// Row L2-normalize (fp32 in) -> bf16 out. One block (256 thr) per row of 4096.
// ---------------------------------------------------------------------------
__global__ __launch_bounds__(256)
void rownorm_bf16(const float* __restrict__ in, short* __restrict__ out)
{
  const int row = blockIdx.x;
  const int t0  = threadIdx.x;
  const float4* inr = (const float4*)(in + (size_t)row * DIM);

  float4 v[4];
  float ss = 0.f;
#pragma unroll
  for (int t = 0; t < 4; ++t) {
    v[t] = inr[t0 + t * 256];
    ss += v[t].x * v[t].x + v[t].y * v[t].y + v[t].z * v[t].z + v[t].w * v[t].w;
  }
#pragma unroll
  for (int off = 32; off > 0; off >>= 1)
    ss += __shfl_down(ss, off, 64);

  __shared__ float wss[4];
  if ((t0 & 63) == 0) wss[t0 >> 6] = ss;
  __syncthreads();
  const float tot   = wss[0] + wss[1] + wss[2] + wss[3];
  const float scale = 1.f / fmaxf(sqrtf(tot), 1e-12f);  // F.normalize eps

  short4* outr = (short4*)(out + (size_t)row * DIM);
#pragma unroll
  for (int t = 0; t < 4; ++t) {
    short4 o;
    o.x = f2bf(v[t].x * scale);
    o.y = f2bf(v[t].y * scale);
    o.z = f2bf(v[t].z * scale);
    o.w = f2bf(v[t].w * scale);
    outr[t0 + t * 256] = o;
  }
}

// ---------------------------------------------------------------------------
// W (fp32 [N][K]) -> fragment-tiled bf16.
// frag f = nb*(K/32)+kb; out[(f*64+l)*8 + e] = W[nb*16+(l&15)][kb*32+(l>>4)*8+e]
// ---------------------------------------------------------------------------
__global__ __launch_bounds__(256)
void cast_w_tiled(const float* __restrict__ in, short* __restrict__ out,
                  int N, int K)
{
  const int KB = K >> 5;
  const int total = (N >> 4) * KB * 64;
  int i = blockIdx.x * 256 + threadIdx.x;
  const int stride = gridDim.x * 256;
  for (; i < total; i += stride) {
    const int l  = i & 63;
    const int f  = i >> 6;
    const int kb = f % KB;
    const int nb = f / KB;
    const int row = nb * 16 + (l & 15);
    const int k0  = kb * 32 + (l >> 4) * 8;
    const float4 v0 = *(const float4*)(in + (size_t)row * K + k0);
    const float4 v1 = *(const float4*)(in + (size_t)row * K + k0 + 4);
    short8 o;
    o[0] = f2bf(v0.x); o[1] = f2bf(v0.y); o[2] = f2bf(v0.z); o[3] = f2bf(v0.w);
    o[4] = f2bf(v1.x); o[5] = f2bf(v1.y); o[6] = f2bf(v1.z); o[7] = f2bf(v1.w);
    *reinterpret_cast<short8*>(out + (size_t)i * 8) = o;
  }
}

extern "C" void kernel_launch(void* const* d_in, const int* in_sizes, int n_in,
                              void* d_out, int out_size, void* d_ws, size_t ws_size,
                              hipStream_t stream) {
  const float* x = (const float*)d_in[0];
  const float* W[3]    = { (const float*)d_in[1], (const float*)d_in[3], (const float*)d_in[5] };
  const float* bias[3] = { (const float*)d_in[2], (const float*)d_in[4], (const float*)d_in[6] };
  float* out = (float*)d_out;

  // workspace: hn bf16 [8192][4096] (64 MiB) | Wt bf16 frag-tiled (32 MiB)
  short* hn = (short*)d_ws;
  short* Wt = (short*)((char*)d_ws + (size_t)NROWS * DIM * 2);

  const size_t layer_elems = (size_t)NROWS * DIM;
  const float* hin = x;

  for (int L = 0; L < 3; ++L) {
    cast_w_tiled<<<2048, 256, 0, stream>>>(W[L], Wt, DIM, DIM);
    rownorm_bf16<<<NROWS, 256, 0, stream>>>(hin, hn);
    gemm256_bias_relu<<<(NROWS / 256) * (DIM / 256), 512, 0, stream>>>(
        hn, Wt, bias[L], out + (size_t)L * layer_elems, NROWS, DIM, DIM);
    hin = out + (size_t)L * layer_elems;
  }
}

// Round 9
// 807.821 us; speedup vs baseline: 1.0299x; 1.0299x over previous
//
#include <hip/hip_runtime.h>
#include <hip/hip_bf16.h>

// Problem: B=8192 rows, D=4096. 3 layers of relu(l2norm(h) @ W^T + b).
// GEMM: 256x256 tile, BK=64, 8 waves, 16x16x32 MFMA, 2 phases/K-tile.
// ROUND 9 = R6 (best, 230us) + A TRIPLE-BUFFER + counted vmcnt(4).
// Diagnosis: R6's ph1 VMW(0) drained A(t+1) staged only ~2000cyc earlier
// (HBM-miss ~900cyc + queueing -> exposed); R8 (shallower covers) was
// worse, confirming latency-cover sensitivity. Now A(t+2) staged at ph0(t)
// (2-tile cover) and ph1 waits vmcnt(4): A(t+2) stays in flight across the
// barrier (T4 counted-vmcnt); steady state never drains to 0.
// LDS = 160 KiB exactly: A x3 (32K each) + B x2.
//
// Steady state tile t (A slot rotates a0/a1/a2, B parity t&1):
//  ph0: stage A(t+2)->a2 | read bF(t) x8 | BAR | GATE [aX(t),bF(t)] |
//       window aY(t)<-a0 x8 | MFMA16(acc[0..3], aX, bF)
//  ph1: VMW(4) [retires A(t+1),B(t+1); leaves A(t+2)] | BAR | GATE [aY] |
//       stage B(t+2) (same buf as B(t)) | window aX(t+1)<-a1 x8 |
//       MFMA16(acc[4..7], aY, bF)
// FIFO ledger (induction): after ph1(t)'s VMW(4): outstanding = A(t+2)x4.
// ph0(t+1) has no vmcnt wait; ph1(t+1) pre-wait queue =
// [A(t+2),B(t+2),A(t+3)] = 12 -> VMW(4) retires A(t+2)+B(t+2). Base: after
// prologue VMW(0): 0; ph0(0) issues A(2) -> ph1(0) VMW(4) no-op. Tail
// t>=NT-2: VMW(0). RAW: aX(t+1) read after ph1's wait retired A(t+1) +
// BAR publish; bF(t) read after ph1(t-1) retired B(t) + BAR. WAR: every
// stage is issued after a barrier that follows its victims' readers' lgkm0.
// Prologue: stage A0,A1,B0,B1; VMW(0) (counted wait would depend on
// compiler issue order across independent ops -- the R7 bug); BAR; aX(0).

#define NROWS 8192
#define DIM   4096

typedef __bf16 bf16x8 __attribute__((ext_vector_type(8)));
typedef float  f32x4  __attribute__((ext_vector_type(4)));

__device__ static inline short f2bf(float f) {
  __hip_bfloat16 h = __float2bfloat16(f);
  return __builtin_bit_cast(short, h);
}

#define BARRIER() do { asm volatile("" ::: "memory"); \
                       __builtin_amdgcn_s_barrier();  \
                       asm volatile("" ::: "memory"); } while (0)
#define GATE()   do { asm volatile("s_waitcnt lgkmcnt(0)" ::: "memory"); \
                      __builtin_amdgcn_sched_barrier(0); } while (0)
#define VMW(N)   do { asm volatile("s_waitcnt vmcnt(" #N ")" ::: "memory"); \
                      __builtin_amdgcn_sched_barrier(0); } while (0)

__global__ __launch_bounds__(512, 2)
void gemm256_bias_relu(const short* __restrict__ A,
                       const short* __restrict__ Bw,
                       const float* __restrict__ bias,
                       float* __restrict__ C,
                       int M, int N, int K)
{
  __shared__ short lds[5][16384];   // 160 KiB: A slots 0..2, B slots 3..4

  // XCD-aware swizzle (bijective: grid % 8 == 0 here)
  int bid = blockIdx.x;
  const int nwg = gridDim.x;
  if ((nwg & 7) == 0) { const int cpx = nwg >> 3; bid = (bid & 7) * cpx + (bid >> 3); }
  const int nbn  = N >> 8;
  const int brow = (bid / nbn) << 8;
  const int bcol = (bid % nbn) << 8;

  const int lane = threadIdx.x & 63;
  const int wid  = threadIdx.x >> 6;   // 0..7
  const int wr   = wid >> 2;           // 0..1 : 128-row band
  const int wc   = wid & 3;            // 0..3 : 64-col band

  f32x4 acc[8][4] = {};

  const size_t rowK = (size_t)K * 2;   // bytes per global row
  char* const  ldsB = (char*)&lds[0][0];

  // ---- staging addressing (coalesced, source pre-swizzled) ----
  const int r8  = lane >> 3;
  const int kcs = (lane & 7) ^ r8;
  const char* AgL = (const char*)A  + (size_t)(brow + r8) * rowK + (size_t)kcs * 16;
  const char* BgL = (const char*)Bw + (size_t)(bcol + r8) * rowK + (size_t)kcs * 16;
  int rbo[4], rbb[4];
#pragma unroll
  for (int i = 0; i < 4; ++i) {
    const int rb = wid * 8 + i * 64;
    rbo[i] = rb * (int)rowK;
    rbb[i] = rb * 128;
  }
  // stage a full 256-row operand tile: 4 x global_load_lds(16B) per thread
  auto stage = [&](const char* gsrc, char* lb, int tile) {
    const char* gp = gsrc + ((size_t)tile << 7);
#pragma unroll
    for (int s = 0; s < 4; ++s)
      __builtin_amdgcn_global_load_lds(
          (const __attribute__((address_space(1))) void*)(gp + rbo[s]),
          (__attribute__((address_space(3))) void*)(lb + rbb[s]), 16, 0, 0);
  };

  // ---- fragment read addressing (swizzled: phys kc = kc ^ (row&7)) ----
  const int l15  = lane & 15;
  const int xlo  = ((lane >> 4) ^ (lane & 3)) * 16;
  const int b2   = (lane >> 2) & 1;
  const int k64[2] = { b2 << 6, (1 - b2) << 6 };
  const int abase = (wr * 128 + l15) * 128 + xlo;
  const int bbase = (wc * 64  + l15) * 128 + xlo;

  const int NT = K >> 6;

  bf16x8 aX[4][2], aY[4][2], bF[4][2];

#define LOAD_FRAG(DST, PTR, BASE, I0)                                        \
  _Pragma("unroll")                                                          \
  for (int ii = 0; ii < 4; ++ii)                                             \
    _Pragma("unroll")                                                        \
    for (int ks = 0; ks < 2; ++ks)                                           \
      DST[ii][ks] = *reinterpret_cast<const bf16x8*>(                        \
          (PTR) + (BASE) + ((I0) + ii) * 2048 + k64[ks]);

// ks outer: same-acc revisit distance = 16 instructions
#define MFMA16(I0, AF)                                                       \
  _Pragma("unroll")                                                          \
  for (int ks = 0; ks < 2; ++ks)                                             \
    _Pragma("unroll")                                                        \
    for (int ii = 0; ii < 4; ++ii)                                           \
      _Pragma("unroll")                                                      \
      for (int j = 0; j < 4; ++j)                                            \
        acc[(I0) + ii][j] = __builtin_amdgcn_mfma_f32_16x16x32_bf16(         \
            AF[ii][ks], bF[j][ks], acc[(I0) + ii][j], 0, 0, 0);

  // rotating A slots (a0 = tile t, a1 = t+1, a2 = t+2) and B parity
  char* a0 = ldsB;
  char* a1 = ldsB + 32768;
  char* a2 = ldsB + 65536;
  char* b0 = ldsB + 98304;           // B(t) -- and B(t+2) target
  char* b1 = ldsB + 131072;          // B(t+1)

  // ---- prologue: A0,A1,B0,B1; full drain; publish; pre-read aX(0) ----
  stage(AgL, a0, 0);
  if (NT > 1) stage(AgL, a1, 1);
  stage(BgL, b0, 0);
  if (NT > 1) stage(BgL, b1, 1);
  VMW(0);
  BARRIER();
  LOAD_FRAG(aX, a0, abase, 0)

  for (int t = 0; t < NT; ++t) {
    // ---- phase 0 ----
    if (t + 2 < NT) stage(AgL, a2, t + 2);
    LOAD_FRAG(bF, b0, bbase, 0)
    BARRIER();
    GATE();                              // aX(t) + bF(t) ready
    LOAD_FRAG(aY, a0, abase, 4)          // window: overlaps MFMA
    __builtin_amdgcn_s_setprio(1);
    MFMA16(0, aX)
    __builtin_amdgcn_s_setprio(0);

    // ---- phase 1 ----
    if (t + 2 < NT) { VMW(4); }          // retire A(t+1),B(t+1); A(t+2) flies
    else            { VMW(0); }
    BARRIER();
    GATE();                              // aY ready
    if (t + 2 < NT) stage(BgL, b0, t + 2);   // same buf as B(t): readers gated
    if (t + 1 < NT) { LOAD_FRAG(aX, a1, abase, 0) }  // next tile's aX
    __builtin_amdgcn_s_setprio(1);
    MFMA16(4, aY)
    __builtin_amdgcn_s_setprio(0);

    // rotate buffers
    char* tmp = a0; a0 = a1; a1 = a2; a2 = tmp;
    char* tb = b0; b0 = b1; b1 = tb;
  }
#undef MFMA16
#undef LOAD_FRAG

  // epilogue (bias loaded here to keep loop regs lean)
  float bv[4];
#pragma unroll
  for (int j = 0; j < 4; ++j)
    bv[j] = bias[bcol + wc * 64 + j * 16 + (lane & 15)];
#pragma unroll
  for (int i = 0; i < 8; ++i) {
    const int rbase = brow + wr * 128 + i * 16 + ((lane >> 4) << 2);
#pragma unroll
    for (int j = 0; j < 4; ++j) {
      const int col = bcol + wc * 64 + j * 16 + (lane & 15);
#pragma unroll
      for (int r = 0; r < 4; ++r) {
        const float v = acc[i][j][r] + bv[j];
        C[(size_t)(rbase + r) * N + col] = v > 0.f ? v : 0.f;
      }
    }
  }
}

// ---------------------------------------------------------------------------
// Row L2-normalize (fp32 in) -> bf16 out. One block (256 thr) per row of 4096.
// ---------------------------------------------------------------------------
__global__ __launch_bounds__(256)
void rownorm_bf16(const float* __restrict__ in, short* __restrict__ out)
{
  const int row = blockIdx.x;
  const int t0  = threadIdx.x;
  const float4* inr = (const float4*)(in + (size_t)row * DIM);

  float4 v[4];
  float ss = 0.f;
#pragma unroll
  for (int t = 0; t < 4; ++t) {
    v[t] = inr[t0 + t * 256];
    ss += v[t].x * v[t].x + v[t].y * v[t].y + v[t].z * v[t].z + v[t].w * v[t].w;
  }
#pragma unroll
  for (int off = 32; off > 0; off >>= 1)
    ss += __shfl_down(ss, off, 64);

  __shared__ float wss[4];
  if ((t0 & 63) == 0) wss[t0 >> 6] = ss;
  __syncthreads();
  const float tot   = wss[0] + wss[1] + wss[2] + wss[3];
  const float scale = 1.f / fmaxf(sqrtf(tot), 1e-12f);  // F.normalize eps

  short4* outr = (short4*)(out + (size_t)row * DIM);
#pragma unroll
  for (int t = 0; t < 4; ++t) {
    short4 o;
    o.x = f2bf(v[t].x * scale);
    o.y = f2bf(v[t].y * scale);
    o.z = f2bf(v[t].z * scale);
    o.w = f2bf(v[t].w * scale);
    outr[t0 + t * 256] = o;
  }
}

// ---------------------------------------------------------------------------
// fp32 -> bf16 bulk cast (for W), vectorized, grid-stride.
// ---------------------------------------------------------------------------
__global__ __launch_bounds__(256)
void cast_bf16(const float* __restrict__ in, short* __restrict__ out, int n4)
{
  int i = blockIdx.x * 256 + threadIdx.x;
  const int stride = gridDim.x * 256;
  for (; i < n4; i += stride) {
    const float4 v = ((const float4*)in)[i];
    short4 o;
    o.x = f2bf(v.x);
    o.y = f2bf(v.y);
    o.z = f2bf(v.z);
    o.w = f2bf(v.w);
    ((short4*)out)[i] = o;
  }
}

extern "C" void kernel_launch(void* const* d_in, const int* in_sizes, int n_in,
                              void* d_out, int out_size, void* d_ws, size_t ws_size,
                              hipStream_t stream) {
  const float* x = (const float*)d_in[0];
  const float* W[3]    = { (const float*)d_in[1], (const float*)d_in[3], (const float*)d_in[5] };
  const float* bias[3] = { (const float*)d_in[2], (const float*)d_in[4], (const float*)d_in[6] };
  float* out = (float*)d_out;

  // workspace layout: hn bf16 [8192][4096] (64 MiB) | Wb bf16 [4096][4096] (32 MiB)
  short* hn = (short*)d_ws;
  short* Wb = (short*)((char*)d_ws + (size_t)NROWS * DIM * 2);

  const size_t layer_elems = (size_t)NROWS * DIM;
  const float* hin = x;

  for (int L = 0; L < 3; ++L) {
    cast_bf16<<<2048, 256, 0, stream>>>(W[L], Wb, DIM * DIM / 4);
    rownorm_bf16<<<NROWS, 256, 0, stream>>>(hin, hn);
    gemm256_bias_relu<<<(NROWS / 256) * (DIM / 256), 512, 0, stream>>>(
        hn, Wb, bias[L], out + (size_t)L * layer_elems, NROWS, DIM, DIM);
    hin = out + (size_t)L * layer_elems;
  }
}